// Round 10
// baseline (177.544 us; speedup 1.0000x reference)
//
#include <hip/hip_runtime.h>
#include <hip/hip_bf16.h>

#define NV 16384
#define NC 16
#define NL 6
#define ND 64

typedef unsigned short u16;
typedef unsigned int u32;
typedef __attribute__((ext_vector_type(8))) short short8;
typedef __attribute__((ext_vector_type(4))) float f32x4;

// ---- pbuf (fp32) offsets, pbuf = (float*)((char*)ws + 256) ----
#define PB_BN  0
#define PB_FE  64
#define PB_B1V 128
#define PB_B2V 192
#define PB_B1C 256
#define PB_B2C 320
// ---- bf16 regions, offsets in u16 elements from (u16*)ws ----
#define U_BVS   896       // clause-B swizzled [gk(12)][nt(8)][lane(64)][8]
#define U_BCS   50048     // var-B swizzled [ks(32)][nt(8)][lane(64)][8]
#define U_VARSB 185216    // [NV+1][64] bf16 vars; row NV = false_emb
#define U_NEGB  1233856   // [NV+1][64] bf16 negvar; row NV = true_emb
#define U_FIDX  2282496   // [NV][96] u16 fused row index (c*6+l)

__device__ __forceinline__ float ldbf(const u16* p, int i) {
  return __uint_as_float(((u32)p[i]) << 16);
}
__device__ __forceinline__ u16 f2b(float f) {  // RNE f32->bf16
  u32 x = __float_as_uint(f);
  return (u16)((x + 0x7FFF + ((x >> 16) & 1)) >> 16);
}
__device__ __forceinline__ int ldmask(const void* p, int i, int bdt) {
  return bdt ? (int)((const signed char*)p)[i] : ((const int*)p)[i];
}
__device__ __forceinline__ float ldf(const void* p, int i, int fdt) {
  return fdt ? ldbf((const u16*)p, i) : ((const float*)p)[i];
}
// async global->LDS, 16 B per lane; LDS dest = uniform base + lane*16
__device__ __forceinline__ void gll16(const u16* g, u16* l) {
  __builtin_amdgcn_global_load_lds(
      (const __attribute__((address_space(1))) u32*)(g),
      (__attribute__((address_space(3))) u32*)(l), 16, 0, 0);
}

// ---------- merged prep (now includes negvar) ----------
// bid 0: flags+params; 1..24: BVS; 25..88: BCS; 89..600: cvt; 601..2136: fidx;
// 2137..2393: negvar (self-contained: reads only original inputs)
__global__ __launch_bounds__(256) void k_prep(
    const void* vars, const int* __restrict__ lits, const void* negm, const void* vval,
    const void* Wn, const void* bn, const void* femb,
    const void* W1v, const void* b1v, const void* W2v, const void* b2v,
    const void* W1c, const void* b1c, const void* W2c, const void* b2c,
    int* flags, float* pbuf, u16* wsB) {
  __shared__ int s_cnt[4], s_big[4];
  __shared__ __align__(16) u16 BnL[4096];
  const int t = threadIdx.x;
  {
    const u32 w = ((const u32*)vars)[t];
    const u32 e = (w >> 7) & 0xFF;
    const unsigned long long bal = __ballot(e >= 0x6E && e <= 0x8E);
    const u32 bw = ((const u32*)vval)[t];
    const unsigned long long bb = __ballot(bw > 1u);
    if ((t & 63) == 0) { s_cnt[t >> 6] = __popcll(bal); s_big[t >> 6] = (bb != 0ull); }
  }
  __syncthreads();
  const int fdt = (s_cnt[0] + s_cnt[1] + s_cnt[2] + s_cnt[3]) >= 192;
  const int bdt = (s_big[0] | s_big[1] | s_big[2] | s_big[3]);
  const int bid = blockIdx.x;

  if (bid == 0) {
    if (t == 0) { flags[0] = fdt; flags[1] = bdt; }
    if (t < 64) {
      const void* src[6] = {bn, femb, b1v, b2v, b1c, b2c};
      const int off[6] = {PB_BN, PB_FE, PB_B1V, PB_B2V, PB_B1C, PB_B2C};
      for (int j = 0; j < 6; j++) pbuf[off[j] + t] = ldf(src[j], t, fdt);
      wsB[U_VARSB + NV * 64 + t] = fdt ? ((const u16*)femb)[t] : f2b(((const float*)femb)[t]);
    }
  } else if (bid < 25) {
    const int c = (bid - 1) * 256 + t;            // 0..6143
    const int ln = c & 63, nt = (c >> 6) & 7, ks = c >> 9;  // ks 0..11
    const int n = nt * 16 + (ln & 15);
    const void* src = (n < 64) ? W1v : W2v;
    const int kb = ks * 32 + (ln >> 4) * 8, n6 = n & 63;
    u16 o[8];
#pragma unroll
    for (int j = 0; j < 8; j++) o[j] = f2b(ldf(src, (kb + j) * 64 + n6, fdt));
    *(short8*)(wsB + U_BVS + c * 8) = *(short8*)o;
  } else if (bid < 89) {
    const int c = (bid - 25) * 256 + t;           // 0..16383
    const int ln = c & 63, nt = (c >> 6) & 7, ks = c >> 9;  // ks 0..31
    const int n = nt * 16 + (ln & 15);
    const void* src = (n < 64) ? W1c : W2c;
    const int kb = ks * 32 + (ln >> 4) * 8, n6 = n & 63;
    u16 o[8];
#pragma unroll
    for (int j = 0; j < 8; j++) o[j] = f2b(ldf(src, (kb + j) * 64 + n6, fdt));
    *(short8*)(wsB + U_BCS + c * 8) = *(short8*)o;
  } else if (bid < 601) {
    const int c8 = (bid - 89) * 256 + t;
    u16 o[8];
    if (fdt) {
      *(short8*)o = ((const short8*)vars)[c8];
    } else {
      const float* f = (const float*)vars + c8 * 8;
#pragma unroll
      for (int j = 0; j < 8; j++) o[j] = f2b(f[j]);
    }
    *(short8*)(wsB + U_VARSB + c8 * 8) = *(short8*)o;
  } else if (bid < 2137) {
    const int i0 = ((bid - 601) * 256 + t) * 4;
    u16 o[4];
#pragma unroll
    for (int j = 0; j < 4; j++) {
      const int i = i0 + j;
      const int valid = ldmask(vval, i, bdt);
      const int neg = ldmask(negm, i, bdt);
      const int idx = lits[i];
      o[j] = (u16)(valid ? (idx + (neg ? (NV + 1) : 0)) : NV);
    }
    *(ushort4*)(wsB + U_FIDX + i0) = *(ushort4*)o;
  } else {
    // negvar: rows rowbase..rowbase+63; reads ONLY original inputs (vars/femb/Wn/bn)
    const int lane = t & 63, wv = t >> 6;
    const int col = lane & 15, quad = lane >> 4, q8 = quad * 8;
    const int rowbase = (bid - 2137) * 64 + wv * 16;
    // transpose Wn into LDS: BnL[n*64+k] = Wn[k][n]
    for (int i = t; i < 4096; i += 256) {
      const int n = i >> 6, k = i & 63;
      BnL[i] = f2b(ldf(Wn, k * 64 + n, fdt));
    }
    __syncthreads();
    const int arow = min(rowbase + col, NV);
    short8 a[2];
    if (fdt) {
      const u16* src = (arow == NV) ? (const u16*)femb : (const u16*)vars + arow * 64;
      a[0] = *(const short8*)(src + q8);
      a[1] = *(const short8*)(src + 32 + q8);
    } else {
      const float* src = (arow == NV) ? (const float*)femb : (const float*)vars + arow * 64;
      u16 tmp[16];
#pragma unroll
      for (int j = 0; j < 8; j++) tmp[j] = f2b(src[q8 + j]);
#pragma unroll
      for (int j = 0; j < 8; j++) tmp[8 + j] = f2b(src[32 + q8 + j]);
      a[0] = *(short8*)tmp;
      a[1] = *(short8*)(tmp + 8);
    }
    f32x4 acc[4];
#pragma unroll
    for (int nt = 0; nt < 4; nt++) acc[nt] = (f32x4){0.f, 0.f, 0.f, 0.f};
#pragma unroll
    for (int ks = 0; ks < 2; ks++) {
#pragma unroll
      for (int nt = 0; nt < 4; nt++) {
        const short8 b = *(const short8*)(BnL + (nt * 16 + col) * 64 + ks * 32 + q8);
        acc[nt] = __builtin_amdgcn_mfma_f32_16x16x32_bf16(a[ks], b, acc[nt], 0, 0, 0);
      }
    }
#pragma unroll
    for (int reg = 0; reg < 4; reg++) {
      const int r = rowbase + quad * 4 + reg;
      if (r <= NV) {
#pragma unroll
        for (int nt = 0; nt < 4; nt++) {
          const int d = nt * 16 + col;
          wsB[U_NEGB + r * 64 + d] = f2b(acc[nt][reg] + ldf(bn, d, fdt));
        }
      }
    }
  }
}

// ---------- fused clause + var combiner: 2 vars/wave, 8 vars/block ----------
__global__ __launch_bounds__(256) void k_main(
    const void* __restrict__ vars, const void* __restrict__ cval,
    const float* __restrict__ pbuf, const int* __restrict__ flags,
    const u16* __restrict__ wsB, void* __restrict__ outv) {
  // phase 1: smem = B double-buffer [2][12288] (48 KB)
  // phase 2: smem[0..16383] = clause_emb swizzled [ks(32)][lane(64)][8]
  __shared__ __align__(16) u16 smem[24576];
  __shared__ float ps[16][4];
  __shared__ int hcS[8];

  const int tid = threadIdx.x, lane = tid & 63, wv = tid >> 6;
  const int col = lane & 15, quad = lane >> 4, q8 = quad * 8;
  const int fdt = flags[0], bdt = flags[1];
  const int vbase = blockIdx.x * 8 + wv * 2;   // this wave: vars vbase, vbase+1
  const int v0 = blockIdx.x * 8;

  // packed fidx: r2_[v4][i] = literals 2i,2i+1 of clause `col` of var vbase+v4
  u32 r2_[2][3];
#pragma unroll
  for (int v4 = 0; v4 < 2; v4++)
#pragma unroll
    for (int i = 0; i < 3; i++)
      r2_[v4][i] = *(const u32*)(wsB + U_FIDX + (vbase + v4) * 96 + col * 6 + i * 2);

  // clause-valid: lanes 0..31 <-> 2 vars x 16 clauses
  int cv = 0;
  if (lane < 32) cv = ldmask(cval, (vbase + (lane >> 4)) * NC + (lane & 15), bdt);
  const unsigned long long bal = __ballot(cv != 0);
  if (lane < 2) hcS[wv * 2 + lane] = ((bal >> (lane * 16)) & 0xFFFFull) != 0;

  f32x4 acc[2][8];
#pragma unroll
  for (int v4 = 0; v4 < 2; v4++)
#pragma unroll
    for (int nt = 0; nt < 8; nt++) acc[v4][nt] = (f32x4){0.f, 0.f, 0.f, 0.f};

  // stage quarter 0 into buf 0 (6 chunks of 1 KB per wave)
#pragma unroll
  for (int j = 0; j < 6; j++) {
    const int cl = wv * 6 + j;
    gll16(wsB + U_BVS + cl * 512 + lane * 8, &smem[cl * 512]);
  }
  // prefetch A for gk=0
  short8 a_cur[2], a_nxt[2];
#pragma unroll
  for (int v4 = 0; v4 < 2; v4++) {
    const int idx = (int)(r2_[v4][0] & 0xFFFFu);
    a_cur[v4] = *(const short8*)(wsB + U_VARSB + idx * 64 + q8);
  }
  __syncthreads();

  for (int q = 0; q < 4; q++) {
    if (q < 3) {
#pragma unroll
      for (int j = 0; j < 6; j++) {
        const int cl = wv * 6 + j;
        gll16(wsB + U_BVS + (q + 1) * 12288 + cl * 512 + lane * 8,
              &smem[((q + 1) & 1) * 12288 + cl * 512]);
      }
    }
#pragma unroll
    for (int ksl = 0; ksl < 3; ksl++) {
      const int gk = q * 3 + ksl;
      if (gk < 11) {
        const int gn = gk + 1;
        const int goff = (gn & 1) * 32 + q8;
        const int pi = gn >> 2, ph = (gn >> 1) & 1;
#pragma unroll
        for (int v4 = 0; v4 < 2; v4++) {
          const int idx = (int)((r2_[v4][pi] >> (ph * 16)) & 0xFFFFu);
          a_nxt[v4] = *(const short8*)(wsB + U_VARSB + idx * 64 + goff);
        }
      }
#pragma unroll
      for (int nt = 0; nt < 8; nt++) {
        const short8 b = *(const short8*)(&smem[(q & 1) * 12288 + (ksl * 8 + nt) * 512 + lane * 8]);
#pragma unroll
        for (int v4 = 0; v4 < 2; v4++)
          acc[v4][nt] = __builtin_amdgcn_mfma_f32_16x16x32_bf16(a_cur[v4], b, acc[v4][nt], 0, 0, 0);
      }
#pragma unroll
      for (int v4 = 0; v4 < 2; v4++) a_cur[v4] = a_nxt[v4];
    }
    if (q < 3) __syncthreads();
  }
  __syncthreads();  // all waves done reading B before epilogue overwrites smem

  // phase-1 epilogue: normalize, clause-pad, write into smem (A-swizzled, M rows 0..7)
  {
    float b1l[4], b2l[4], truel[4];
#pragma unroll
    for (int nt = 0; nt < 4; nt++) {
      const int d = nt * 16 + col;
      b1l[nt] = pbuf[PB_B1V + d];
      b2l[nt] = pbuf[PB_B2V + d];
      truel[nt] = ldbf(wsB, U_NEGB + NV * 64 + d);
    }
#pragma unroll
    for (int v4 = 0; v4 < 2; v4++) {
      const u32 vmask = (u32)((bal >> (v4 * 16)) & 0xFFFFull);
      const int vloc = wv * 2 + v4;  // 0..7
#pragma unroll
      for (int reg = 0; reg < 4; reg++) {
        const int c = quad * 4 + reg;
        float hh[4], ss = 0.f;
#pragma unroll
        for (int nt = 0; nt < 4; nt++) {
          hh[nt] = 1.0f / (1.0f + __expf(-(acc[v4][nt][reg] + b1l[nt]))) + acc[v4][nt + 4][reg] + b2l[nt];
          ss += hh[nt] * hh[nt];
        }
        ss += __shfl_xor(ss, 1, 64); ss += __shfl_xor(ss, 2, 64);
        ss += __shfl_xor(ss, 4, 64); ss += __shfl_xor(ss, 8, 64);
        const float sc = 1.0f / sqrtf(ss);
        const int valid = (vmask >> c) & 1;
#pragma unroll
        for (int nt = 0; nt < 4; nt++) {
          const float o = valid ? hh[nt] * sc : truel[nt];
          const int l2 = (nt * 2 + (col >> 3)) & 3;
          smem[(c * 2 + (nt >> 1)) * 512 + (l2 * 16 + vloc) * 8 + (col & 7)] = f2b(o);
        }
      }
    }
  }
  __syncthreads();

  // phase 2: var combiner. M=8 (block's vars; rows 8..15 garbage, masked at store).
  f32x4 acc1 = (f32x4){0.f, 0.f, 0.f, 0.f}, acc2 = (f32x4){0.f, 0.f, 0.f, 0.f};
#pragma unroll 8
  for (int ks = 0; ks < 32; ks++) {
    const short8 a = *(const short8*)(&smem[ks * 512 + lane * 8]);
    const short8 b1 = *(const short8*)(wsB + U_BCS + (ks * 8 + wv) * 512 + lane * 8);
    const short8 b2 = *(const short8*)(wsB + U_BCS + (ks * 8 + wv + 4) * 512 + lane * 8);
    acc1 = __builtin_amdgcn_mfma_f32_16x16x32_bf16(a, b1, acc1, 0, 0, 0);
    acc2 = __builtin_amdgcn_mfma_f32_16x16x32_bf16(a, b2, acc2, 0, 0, 0);
  }

  const int d = wv * 16 + col;
  const float b1c_d = pbuf[PB_B1C + d], b2c_d = pbuf[PB_B2C + d];
  float h[4];
#pragma unroll
  for (int reg = 0; reg < 4; reg++) {
    h[reg] = 1.0f / (1.0f + __expf(-(acc1[reg] + b1c_d))) + acc2[reg] + b2c_d;
    float ssp = h[reg] * h[reg];
    ssp += __shfl_xor(ssp, 1, 64); ssp += __shfl_xor(ssp, 2, 64);
    ssp += __shfl_xor(ssp, 4, 64); ssp += __shfl_xor(ssp, 8, 64);
    if (col == 0) ps[quad * 4 + reg][wv] = ssp;
  }
  __syncthreads();
#pragma unroll
  for (int reg = 0; reg < 4; reg++) {
    const int r = quad * 4 + reg;
    if (r < 8) {
      const float tot = ps[r][0] + ps[r][1] + ps[r][2] + ps[r][3];
      float o = h[reg] * (1.0f / sqrtf(tot));
      const int oi = (v0 + r) * 64 + d;
      if (hcS[r]) {
        if (fdt) ((u16*)outv)[oi] = f2b(o);
        else ((float*)outv)[oi] = o;
      } else {
        if (fdt) ((u16*)outv)[oi] = ((const u16*)vars)[oi];
        else ((float*)outv)[oi] = ((const float*)vars)[oi];
      }
    }
  }
}

extern "C" void kernel_launch(void* const* d_in, const int* in_sizes, int n_in,
                              void* d_out, int out_size, void* d_ws, size_t ws_size,
                              hipStream_t stream) {
  const void* vars = d_in[0];
  const int* lits = (const int*)d_in[1];
  const void* negm = d_in[2];
  const void* vval = d_in[3];
  const void* cvalid = d_in[4];
  const void* Wn = d_in[5];
  const void* bn = d_in[6];
  const void* femb = d_in[7];
  const void* W1v = d_in[8];
  const void* b1v = d_in[9];
  const void* W2v = d_in[10];
  const void* b2v = d_in[11];
  const void* W1c = d_in[12];
  const void* b1c = d_in[13];
  const void* W2c = d_in[14];
  const void* b2c = d_in[15];

  int* flags = (int*)d_ws;
  float* pbuf = (float*)((char*)d_ws + 256);
  u16* wsB = (u16*)d_ws;

  k_prep<<<2394, 256, 0, stream>>>(vars, lits, negm, vval, Wn, bn, femb,
                                   W1v, b1v, W2v, b2v, W1c, b1c, W2c, b2c,
                                   flags, pbuf, wsB);
  k_main<<<NV / 8, 256, 0, stream>>>(vars, cvalid, pbuf, flags, wsB, d_out);
}

// Round 11
// 159.388 us; speedup vs baseline: 1.1139x; 1.1139x over previous
//
#include <hip/hip_runtime.h>
#include <hip/hip_bf16.h>

#define NV 16384
#define NC 16
#define NL 6
#define ND 64

typedef unsigned short u16;
typedef unsigned int u32;
typedef __attribute__((ext_vector_type(8))) short short8;
typedef __attribute__((ext_vector_type(4))) float f32x4;

// ---- pbuf (fp32) offsets, pbuf = (float*)((char*)ws + 256) ----
#define PB_BN  0
#define PB_FE  64
#define PB_B1V 128
#define PB_B2V 192
#define PB_B1C 256
#define PB_B2C 320
// ---- bf16 regions, offsets in u16 elements from (u16*)ws ----
#define U_BVS   896       // clause-B swizzled [gk(12)][nt(8)][lane(64)][8]
#define U_BCS   50048     // var-B swizzled [ks(32)][nt(8)][lane(64)][8]
#define U_VARSB 185216    // [NV+1][64] bf16 vars; row NV = false_emb
#define U_NEGB  1233856   // [NV+1][64] bf16 negvar; row NV = true_emb
#define U_FIDX  2282496   // [NV][96] u16 fused row index (c*6+l)

__device__ __forceinline__ float ldbf(const u16* p, int i) {
  return __uint_as_float(((u32)p[i]) << 16);
}
__device__ __forceinline__ u16 f2b(float f) {  // RNE f32->bf16
  u32 x = __float_as_uint(f);
  return (u16)((x + 0x7FFF + ((x >> 16) & 1)) >> 16);
}
__device__ __forceinline__ int ldmask(const void* p, int i, int bdt) {
  return bdt ? (int)((const signed char*)p)[i] : ((const int*)p)[i];
}
__device__ __forceinline__ float ldf(const void* p, int i, int fdt) {
  return fdt ? ldbf((const u16*)p, i) : ((const float*)p)[i];
}
// async global->LDS, 16 B per lane; LDS dest = uniform base + lane*16
__device__ __forceinline__ void gll16(const u16* g, u16* l) {
  __builtin_amdgcn_global_load_lds(
      (const __attribute__((address_space(1))) u32*)(g),
      (__attribute__((address_space(3))) u32*)(l), 16, 0, 0);
}

// ---------- merged prep ----------
// bid 0: flags+params; 1..24: BVS; 25..88: BCS; 89..216: cvt (4x short8/thread);
// 217..600: fidx (16 lits/thread, int4); 601..857: negvar
__global__ __launch_bounds__(256) void k_prep(
    const void* vars, const int* __restrict__ lits, const void* negm, const void* vval,
    const void* Wn, const void* bn, const void* femb,
    const void* W1v, const void* b1v, const void* W2v, const void* b2v,
    const void* W1c, const void* b1c, const void* W2c, const void* b2c,
    int* flags, float* pbuf, u16* wsB) {
  __shared__ int s_cnt[4], s_big[4];
  __shared__ __align__(16) u16 BnL[4096];
  const int t = threadIdx.x;
  {
    const u32 w = ((const u32*)vars)[t];
    const u32 e = (w >> 7) & 0xFF;
    const unsigned long long bal = __ballot(e >= 0x6E && e <= 0x8E);
    const u32 bw = ((const u32*)vval)[t];
    const unsigned long long bb = __ballot(bw > 1u);
    if ((t & 63) == 0) { s_cnt[t >> 6] = __popcll(bal); s_big[t >> 6] = (bb != 0ull); }
  }
  __syncthreads();
  const int fdt = (s_cnt[0] + s_cnt[1] + s_cnt[2] + s_cnt[3]) >= 192;
  const int bdt = (s_big[0] | s_big[1] | s_big[2] | s_big[3]);
  const int bid = blockIdx.x;

  if (bid == 0) {
    if (t == 0) { flags[0] = fdt; flags[1] = bdt; }
    if (t < 64) {
      const void* src[6] = {bn, femb, b1v, b2v, b1c, b2c};
      const int off[6] = {PB_BN, PB_FE, PB_B1V, PB_B2V, PB_B1C, PB_B2C};
      for (int j = 0; j < 6; j++) pbuf[off[j] + t] = ldf(src[j], t, fdt);
      wsB[U_VARSB + NV * 64 + t] = fdt ? ((const u16*)femb)[t] : f2b(((const float*)femb)[t]);
    }
  } else if (bid < 25) {
    const int c = (bid - 1) * 256 + t;            // 0..6143
    const int ln = c & 63, nt = (c >> 6) & 7, ks = c >> 9;  // ks 0..11
    const int n = nt * 16 + (ln & 15);
    const void* src = (n < 64) ? W1v : W2v;
    const int kb = ks * 32 + (ln >> 4) * 8, n6 = n & 63;
    u16 o[8];
#pragma unroll
    for (int j = 0; j < 8; j++) o[j] = f2b(ldf(src, (kb + j) * 64 + n6, fdt));
    *(short8*)(wsB + U_BVS + c * 8) = *(short8*)o;
  } else if (bid < 89) {
    const int c = (bid - 25) * 256 + t;           // 0..16383
    const int ln = c & 63, nt = (c >> 6) & 7, ks = c >> 9;  // ks 0..31
    const int n = nt * 16 + (ln & 15);
    const void* src = (n < 64) ? W1c : W2c;
    const int kb = ks * 32 + (ln >> 4) * 8, n6 = n & 63;
    u16 o[8];
#pragma unroll
    for (int j = 0; j < 8; j++) o[j] = f2b(ldf(src, (kb + j) * 64 + n6, fdt));
    *(short8*)(wsB + U_BCS + c * 8) = *(short8*)o;
  } else if (bid < 217) {
    // cvt: 4 x short8 chunks per thread (64 B)
    const int c8 = ((bid - 89) * 256 + t) * 4;
#pragma unroll
    for (int cc = 0; cc < 4; cc++) {
      u16 o[8];
      if (fdt) {
        *(short8*)o = ((const short8*)vars)[c8 + cc];
      } else {
        const float* f = (const float*)vars + (c8 + cc) * 8;
#pragma unroll
        for (int j = 0; j < 8; j++) o[j] = f2b(f[j]);
      }
      *(short8*)(wsB + U_VARSB + (c8 + cc) * 8) = *(short8*)o;
    }
  } else if (bid < 601) {
    // fidx: 16 literals per thread, int4 loads
    const int i0 = ((bid - 217) * 256 + t) * 16;
    u16 o[16];
    if (!bdt) {
      const int4* lp = (const int4*)(lits + i0);
      const int4* vp = (const int4*)((const int*)vval + i0);
      const int4* np = (const int4*)((const int*)negm + i0);
#pragma unroll
      for (int c4 = 0; c4 < 4; c4++) {
        const int4 L = lp[c4], V = vp[c4], N = np[c4];
        o[c4 * 4 + 0] = (u16)(V.x ? (L.x + (N.x ? (NV + 1) : 0)) : NV);
        o[c4 * 4 + 1] = (u16)(V.y ? (L.y + (N.y ? (NV + 1) : 0)) : NV);
        o[c4 * 4 + 2] = (u16)(V.z ? (L.z + (N.z ? (NV + 1) : 0)) : NV);
        o[c4 * 4 + 3] = (u16)(V.w ? (L.w + (N.w ? (NV + 1) : 0)) : NV);
      }
    } else {
#pragma unroll
      for (int j = 0; j < 16; j++) {
        const int i = i0 + j;
        const int valid = ldmask(vval, i, bdt);
        const int neg = ldmask(negm, i, bdt);
        o[j] = (u16)(valid ? (lits[i] + (neg ? (NV + 1) : 0)) : NV);
      }
    }
    *(short8*)(wsB + U_FIDX + i0) = *(short8*)o;
    *(short8*)(wsB + U_FIDX + i0 + 8) = *(short8*)(o + 8);
  } else {
    // negvar: rows rowbase..rowbase+63; reads ONLY original inputs (vars/femb/Wn/bn)
    const int lane = t & 63, wv = t >> 6;
    const int col = lane & 15, quad = lane >> 4, q8 = quad * 8;
    const int rowbase = (bid - 601) * 64 + wv * 16;
    for (int i = t; i < 4096; i += 256) {
      const int n = i >> 6, k = i & 63;
      BnL[i] = f2b(ldf(Wn, k * 64 + n, fdt));
    }
    __syncthreads();
    const int arow = min(rowbase + col, NV);
    short8 a[2];
    if (fdt) {
      const u16* src = (arow == NV) ? (const u16*)femb : (const u16*)vars + arow * 64;
      a[0] = *(const short8*)(src + q8);
      a[1] = *(const short8*)(src + 32 + q8);
    } else {
      const float* src = (arow == NV) ? (const float*)femb : (const float*)vars + arow * 64;
      u16 tmp[16];
#pragma unroll
      for (int j = 0; j < 8; j++) tmp[j] = f2b(src[q8 + j]);
#pragma unroll
      for (int j = 0; j < 8; j++) tmp[8 + j] = f2b(src[32 + q8 + j]);
      a[0] = *(short8*)tmp;
      a[1] = *(short8*)(tmp + 8);
    }
    f32x4 acc[4];
#pragma unroll
    for (int nt = 0; nt < 4; nt++) acc[nt] = (f32x4){0.f, 0.f, 0.f, 0.f};
#pragma unroll
    for (int ks = 0; ks < 2; ks++) {
#pragma unroll
      for (int nt = 0; nt < 4; nt++) {
        const short8 b = *(const short8*)(BnL + (nt * 16 + col) * 64 + ks * 32 + q8);
        acc[nt] = __builtin_amdgcn_mfma_f32_16x16x32_bf16(a[ks], b, acc[nt], 0, 0, 0);
      }
    }
#pragma unroll
    for (int reg = 0; reg < 4; reg++) {
      const int r = rowbase + quad * 4 + reg;
      if (r <= NV) {
#pragma unroll
        for (int nt = 0; nt < 4; nt++) {
          const int d = nt * 16 + col;
          wsB[U_NEGB + r * 64 + d] = f2b(acc[nt][reg] + ldf(bn, d, fdt));
        }
      }
    }
  }
}

// ---------- fused clause + var combiner: 4 vars/wave, 16 vars/block (round-9 best) ----------
__global__ __launch_bounds__(256, 2) void k_main(
    const void* __restrict__ vars, const void* __restrict__ cval,
    const float* __restrict__ pbuf, const int* __restrict__ flags,
    const u16* __restrict__ wsB, void* __restrict__ outv) {
  // phase 1: smem = B double-buffer [2][12288] (48 KB)
  // phase 2: smem[0..16383] = clause_emb swizzled [ks(32)][lane(64)][8]
  __shared__ __align__(16) u16 smem[24576];
  __shared__ float ps[16][4];
  __shared__ int hcS[16];

  const int tid = threadIdx.x, lane = tid & 63, wv = tid >> 6;
  const int col = lane & 15, quad = lane >> 4, q8 = quad * 8;
  const int fdt = flags[0], bdt = flags[1];
  const int vbase = (blockIdx.x * 4 + wv) * 4;
  const int v0 = blockIdx.x * 16;

  // packed fidx: r2_[v4][i] = literals 2i,2i+1 of clause `col` of var vbase+v4
  u32 r2_[4][3];
#pragma unroll
  for (int v4 = 0; v4 < 4; v4++)
#pragma unroll
    for (int i = 0; i < 3; i++)
      r2_[v4][i] = *(const u32*)(wsB + U_FIDX + (vbase + v4) * 96 + col * 6 + i * 2);

  const int cv = ldmask(cval, vbase * 16 + lane, bdt);
  const unsigned long long bal = __ballot(cv != 0);
  if (lane < 4) hcS[wv * 4 + lane] = ((bal >> (lane * 16)) & 0xFFFFull) != 0;

  f32x4 acc[4][8];
#pragma unroll
  for (int v4 = 0; v4 < 4; v4++)
#pragma unroll
    for (int nt = 0; nt < 8; nt++) acc[v4][nt] = (f32x4){0.f, 0.f, 0.f, 0.f};

  // stage quarter 0 into buf 0 (6 chunks of 1 KB per wave)
#pragma unroll
  for (int j = 0; j < 6; j++) {
    const int cl = wv * 6 + j;
    gll16(wsB + U_BVS + cl * 512 + lane * 8, &smem[cl * 512]);
  }
  // prefetch A for gk=0
  short8 a_cur[4], a_nxt[4];
#pragma unroll
  for (int v4 = 0; v4 < 4; v4++) {
    const int idx = (int)(r2_[v4][0] & 0xFFFFu);
    a_cur[v4] = *(const short8*)(wsB + U_VARSB + idx * 64 + q8);
  }
  __syncthreads();

  for (int q = 0; q < 4; q++) {
    if (q < 3) {
#pragma unroll
      for (int j = 0; j < 6; j++) {
        const int cl = wv * 6 + j;
        gll16(wsB + U_BVS + (q + 1) * 12288 + cl * 512 + lane * 8,
              &smem[((q + 1) & 1) * 12288 + cl * 512]);
      }
    }
#pragma unroll
    for (int ksl = 0; ksl < 3; ksl++) {
      const int gk = q * 3 + ksl;
      if (gk < 11) {
        const int gn = gk + 1;
        const int goff = (gn & 1) * 32 + q8;
        const int pi = gn >> 2, ph = (gn >> 1) & 1;
#pragma unroll
        for (int v4 = 0; v4 < 4; v4++) {
          const int idx = (int)((r2_[v4][pi] >> (ph * 16)) & 0xFFFFu);
          a_nxt[v4] = *(const short8*)(wsB + U_VARSB + idx * 64 + goff);
        }
      }
#pragma unroll
      for (int nt = 0; nt < 8; nt++) {
        const short8 b = *(const short8*)(&smem[(q & 1) * 12288 + (ksl * 8 + nt) * 512 + lane * 8]);
#pragma unroll
        for (int v4 = 0; v4 < 4; v4++)
          acc[v4][nt] = __builtin_amdgcn_mfma_f32_16x16x32_bf16(a_cur[v4], b, acc[v4][nt], 0, 0, 0);
      }
#pragma unroll
      for (int v4 = 0; v4 < 4; v4++) a_cur[v4] = a_nxt[v4];
    }
    if (q < 3) __syncthreads();
  }
  __syncthreads();  // all waves done reading B before epilogue overwrites smem

  // phase-1 epilogue: normalize, clause-pad, write into smem (A-swizzled for phase 2)
  {
    float b1l[4], b2l[4], truel[4];
#pragma unroll
    for (int nt = 0; nt < 4; nt++) {
      const int d = nt * 16 + col;
      b1l[nt] = pbuf[PB_B1V + d];
      b2l[nt] = pbuf[PB_B2V + d];
      truel[nt] = ldbf(wsB, U_NEGB + NV * 64 + d);
    }
#pragma unroll
    for (int v4 = 0; v4 < 4; v4++) {
      const u32 vmask = (u32)((bal >> (v4 * 16)) & 0xFFFFull);
      const int vloc = wv * 4 + v4;
#pragma unroll
      for (int reg = 0; reg < 4; reg++) {
        const int c = quad * 4 + reg;
        float hh[4], ss = 0.f;
#pragma unroll
        for (int nt = 0; nt < 4; nt++) {
          hh[nt] = 1.0f / (1.0f + __expf(-(acc[v4][nt][reg] + b1l[nt]))) + acc[v4][nt + 4][reg] + b2l[nt];
          ss += hh[nt] * hh[nt];
        }
        ss += __shfl_xor(ss, 1, 64); ss += __shfl_xor(ss, 2, 64);
        ss += __shfl_xor(ss, 4, 64); ss += __shfl_xor(ss, 8, 64);
        const float sc = 1.0f / sqrtf(ss);
        const int valid = (vmask >> c) & 1;
#pragma unroll
        for (int nt = 0; nt < 4; nt++) {
          const float o = valid ? hh[nt] * sc : truel[nt];
          const int l2 = (nt * 2 + (col >> 3)) & 3;
          smem[(c * 2 + (nt >> 1)) * 512 + (l2 * 16 + vloc) * 8 + (col & 7)] = f2b(o);
        }
      }
    }
  }
  __syncthreads();

  // phase 2: var combiner. M=16 (block's vars), K=1024, wave wv -> d cols [wv*16, wv*16+16)
  f32x4 acc1 = (f32x4){0.f, 0.f, 0.f, 0.f}, acc2 = (f32x4){0.f, 0.f, 0.f, 0.f};
#pragma unroll 8
  for (int ks = 0; ks < 32; ks++) {
    const short8 a = *(const short8*)(&smem[ks * 512 + lane * 8]);
    const short8 b1 = *(const short8*)(wsB + U_BCS + (ks * 8 + wv) * 512 + lane * 8);
    const short8 b2 = *(const short8*)(wsB + U_BCS + (ks * 8 + wv + 4) * 512 + lane * 8);
    acc1 = __builtin_amdgcn_mfma_f32_16x16x32_bf16(a, b1, acc1, 0, 0, 0);
    acc2 = __builtin_amdgcn_mfma_f32_16x16x32_bf16(a, b2, acc2, 0, 0, 0);
  }

  const int d = wv * 16 + col;
  const float b1c_d = pbuf[PB_B1C + d], b2c_d = pbuf[PB_B2C + d];
  float h[4];
#pragma unroll
  for (int reg = 0; reg < 4; reg++) {
    h[reg] = 1.0f / (1.0f + __expf(-(acc1[reg] + b1c_d))) + acc2[reg] + b2c_d;
    float ssp = h[reg] * h[reg];
    ssp += __shfl_xor(ssp, 1, 64); ssp += __shfl_xor(ssp, 2, 64);
    ssp += __shfl_xor(ssp, 4, 64); ssp += __shfl_xor(ssp, 8, 64);
    if (col == 0) ps[quad * 4 + reg][wv] = ssp;
  }
  __syncthreads();
#pragma unroll
  for (int reg = 0; reg < 4; reg++) {
    const int r = quad * 4 + reg;
    const float tot = ps[r][0] + ps[r][1] + ps[r][2] + ps[r][3];
    float o = h[reg] * (1.0f / sqrtf(tot));
    const int oi = (v0 + r) * 64 + d;
    if (hcS[r]) {
      if (fdt) ((u16*)outv)[oi] = f2b(o);
      else ((float*)outv)[oi] = o;
    } else {
      if (fdt) ((u16*)outv)[oi] = ((const u16*)vars)[oi];
      else ((float*)outv)[oi] = ((const float*)vars)[oi];
    }
  }
}

extern "C" void kernel_launch(void* const* d_in, const int* in_sizes, int n_in,
                              void* d_out, int out_size, void* d_ws, size_t ws_size,
                              hipStream_t stream) {
  const void* vars = d_in[0];
  const int* lits = (const int*)d_in[1];
  const void* negm = d_in[2];
  const void* vval = d_in[3];
  const void* cvalid = d_in[4];
  const void* Wn = d_in[5];
  const void* bn = d_in[6];
  const void* femb = d_in[7];
  const void* W1v = d_in[8];
  const void* b1v = d_in[9];
  const void* W2v = d_in[10];
  const void* b2v = d_in[11];
  const void* W1c = d_in[12];
  const void* b1c = d_in[13];
  const void* W2c = d_in[14];
  const void* b2c = d_in[15];

  int* flags = (int*)d_ws;
  float* pbuf = (float*)((char*)d_ws + 256);
  u16* wsB = (u16*)d_ws;

  k_prep<<<858, 256, 0, stream>>>(vars, lits, negm, vval, Wn, bn, femb,
                                  W1v, b1v, W2v, b2v, W1c, b1c, W2c, b2c,
                                  flags, pbuf, wsB);
  k_main<<<NV / 16, 256, 0, stream>>>(vars, cvalid, pbuf, flags, wsB, d_out);
}